// Round 13
// baseline (282.970 us; speedup 1.0000x reference)
//
#include <hip/hip_runtime.h>
#include <hip/hip_bf16.h>
#include <math.h>

typedef __bf16 bf16x8 __attribute__((ext_vector_type(8)));
typedef float f32x4 __attribute__((ext_vector_type(4)));

#define CDIM 128

__global__ void sentinel_kernel(float* outf) {
  if (threadIdx.x == 0) outf[0] = 12345.0f;  // ws_size too small signature
}

// ---------------- prep + hist fused (deg3 pre-zeroed by hipMemsetAsync) ------
// blocks [0,48): wt[v][r][kb][o][j] = w_v[r][kb*8+j][o]
// block 48: c = le.e consts + wqk vectors (W_r q, W_r k for both layers)
// blocks [49,...): hist atomics on (etype*N + dst), 4 edges/thread
__global__ __launch_bounds__(256) void prep_hist_kernel(
    const float* __restrict__ w1, const float* __restrict__ w2,
    __hip_bfloat16* __restrict__ wt,
    const float* __restrict__ q1, const float* __restrict__ k1v,
    const float* __restrict__ q2, const float* __restrict__ k2v,
    const float* __restrict__ le1, const float* __restrict__ e1,
    const float* __restrict__ le2, const float* __restrict__ e2,
    float* __restrict__ outc, float* __restrict__ wqk,
    const int* __restrict__ dstv, const int* __restrict__ etype,
    int* __restrict__ deg3, int perW, int n, int E) {
  const int b = blockIdx.x;
  const int tid = threadIdx.x;
  if (b < 48) {
    int t = b * 256 + tid;
    if (t >= perW * 2) return;
    const float* w = (t < perW) ? w1 : w2;
    int tt = (t < perW) ? t : t - perW;
    int r = tt >> 11;
    int rem = tt & 2047;
    int kb = rem >> 7;
    int o = rem & 127;
    const float* wr = w + ((size_t)r << 14);
    union { __hip_bfloat16 h[8]; int4 v; } u;
#pragma unroll
    for (int j = 0; j < 8; ++j)
      u.h[j] = __float2bfloat16(wr[(size_t)(kb * 8 + j) * CDIM + o]);
    *reinterpret_cast<int4*>(wt + (size_t)t * 8) = u.v;
  } else if (b == 48) {
    if (tid < 64) {
      float v1 = le1[tid] * e1[tid] + le1[tid + 64] * e1[tid + 64];
      float v2 = le2[tid] * e2[tid] + le2[tid + 64] * e2[tid + 64];
#pragma unroll
      for (int off = 32; off > 0; off >>= 1) {
        v1 += __shfl_xor(v1, off, 64);
        v2 += __shfl_xor(v2, off, 64);
      }
      if (tid == 0) { outc[0] = v1; outc[1] = v2; }
    }
    // wqk[0..383]=W1q, [384..767]=W1k, [768..1151]=W2q, [1152..1535]=W2k
    for (int idx = tid; idx < 384; idx += 256) {
      int r = idx >> 7, k = idx & 127;
      const float* w1r = w1 + ((size_t)r << 14) + (size_t)k * 128;
      const float* w2r = w2 + ((size_t)r << 14) + (size_t)k * 128;
      float dq1 = 0.f, dk1 = 0.f, dq2 = 0.f, dk2 = 0.f;
      for (int j = 0; j < 128; ++j) {
        float a1 = w1r[j], a2 = w2r[j];
        dq1 += a1 * q1[j];
        dk1 += a1 * k1v[j];
        dq2 += a2 * q2[j];
        dk2 += a2 * k2v[j];
      }
      wqk[idx] = dq1;
      wqk[384 + idx] = dk1;
      wqk[768 + idx] = dq2;
      wqk[1152 + idx] = dk2;
    }
  } else {
    int e0 = (b - 49) * 1024 + tid * 4;
    if (e0 + 3 < E) {
      int4 d4 = *reinterpret_cast<const int4*>(&dstv[e0]);
      int4 t4 = *reinterpret_cast<const int4*>(&etype[e0]);
      atomicAdd(&deg3[t4.x * n + d4.x], 1);
      atomicAdd(&deg3[t4.y * n + d4.y], 1);
      atomicAdd(&deg3[t4.z * n + d4.z], 1);
      atomicAdd(&deg3[t4.w * n + d4.w], 1);
    } else {
      for (int t = 0; t < 4; ++t) {
        int e = e0 + t;
        if (e < E) atomicAdd(&deg3[etype[e] * n + dstv[e]], 1);
      }
    }
  }
}

// ---------------- CSR scans over 3N segments ----------------
// scan1: 4096 elems/block (16/thread) so partials count <= 64
__global__ __launch_bounds__(256) void scan1_kernel(const int* __restrict__ deg3,
                                                    int* __restrict__ rowptr3,
                                                    int* __restrict__ partials, int m3) {
  __shared__ int sh[256];
  int t = threadIdx.x;
  int idx = blockIdx.x * 4096 + t * 16;
  int v[16]; int s = 0;
#pragma unroll
  for (int j = 0; j < 16; ++j) { v[j] = (idx + j < m3) ? deg3[idx + j] : 0; s += v[j]; }
  sh[t] = s;
  __syncthreads();
  for (int off = 1; off < 256; off <<= 1) {
    int x = (t >= off) ? sh[t - off] : 0;
    __syncthreads();
    sh[t] += x;
    __syncthreads();
  }
  int excl = sh[t] - s;
  if (t == 255) partials[blockIdx.x] = sh[255];
  int run = excl;
#pragma unroll
  for (int j = 0; j < 16; ++j) {
    if (idx + j < m3) rowptr3[idx + j] = run;
    run += v[j];
  }
}

// scan3 with inline prefix of partials (nb <= 64); 4096-granular
__global__ __launch_bounds__(256) void scan3_kernel(int* __restrict__ rowptr3,
                                                    int* __restrict__ cursor3,
                                                    const int* __restrict__ partials,
                                                    int nb, int m3, int E) {
  __shared__ int spfx[64];
  int t = threadIdx.x;
  if (t < 64) {
    int pv = (t < nb) ? partials[t] : 0;
    int v = pv;
#pragma unroll
    for (int off = 1; off < 64; off <<= 1) {
      int u = __shfl_up(v, off, 64);
      if (t >= off) v += u;
    }
    spfx[t] = v - pv;  // exclusive prefix
  }
  __syncthreads();
  int i = blockIdx.x * 256 + t;
  if (i < m3) {
    int v = rowptr3[i] + spfx[i >> 12];
    rowptr3[i] = v;
    cursor3[i] = v;
  } else if (i == m3) {
    rowptr3[m3] = E;
  }
}

// ---------------- sqsk + xb cast (blocks [0,NX)) + scatter (rest), fused -----
// sq1[r*N+i] = x_i . (W1_r q1) etc; xb = bf16(x). Scatter keys by etype*N+dst,
// payload (src, eattr bits).
__global__ __launch_bounds__(256) void sqskxb_scatter_kernel(
    const float* __restrict__ x, const float* __restrict__ wqk,
    __hip_bfloat16* __restrict__ xb, float* __restrict__ sq1, float* __restrict__ sk1,
    const int* __restrict__ srcv, const int* __restrict__ dstv,
    const int* __restrict__ etype, const float* __restrict__ eattr,
    int* __restrict__ cursor3, int2* __restrict__ kattr,
    int NX, int n, int E) {
  __shared__ float wls[768];  // wq1[3][128], wk1[3][128]
  const int b = blockIdx.x;
  const int tid = threadIdx.x;
  if (b < NX) {
    for (int i = tid; i < 768; i += 256) wls[i] = wqk[i];
    __syncthreads();
    const int row = b * 128 + (tid >> 1);
    const int half = tid & 1;
    if (row >= n) return;
    const float* xp = x + (size_t)row * CDIM + half * 64;
    __hip_bfloat16* xbp = xb + (size_t)row * CDIM + half * 64;
    float a0 = 0.f, a1 = 0.f, a2 = 0.f, a3 = 0.f, a4 = 0.f, a5 = 0.f;
#pragma unroll
    for (int i = 0; i < 16; ++i) {
      f32x4 v = *reinterpret_cast<const f32x4*>(xp + i * 4);
      union { __hip_bfloat16 h[4]; uint2 u; } pk;
#pragma unroll
      for (int j = 0; j < 4; ++j) pk.h[j] = __float2bfloat16(v[j]);
      *reinterpret_cast<uint2*>(xbp + i * 4) = pk.u;
      const int cb = half * 64 + i * 4;
#pragma unroll
      for (int j = 0; j < 4; ++j) {
        float xv = v[j];
        a0 += xv * wls[cb + j];
        a1 += xv * wls[128 + cb + j];
        a2 += xv * wls[256 + cb + j];
        a3 += xv * wls[384 + cb + j];
        a4 += xv * wls[512 + cb + j];
        a5 += xv * wls[640 + cb + j];
      }
    }
    a0 += __shfl_xor(a0, 1, 64);
    a1 += __shfl_xor(a1, 1, 64);
    a2 += __shfl_xor(a2, 1, 64);
    a3 += __shfl_xor(a3, 1, 64);
    a4 += __shfl_xor(a4, 1, 64);
    a5 += __shfl_xor(a5, 1, 64);
    if (half == 0) {
      sq1[row] = a0; sq1[n + row] = a1; sq1[2 * n + row] = a2;
      sk1[row] = a3; sk1[n + row] = a4; sk1[2 * n + row] = a5;
    }
  } else {
    int e0 = (b - NX) * 1024 + tid * 4;
    if (e0 + 3 < E) {
      int4 s4 = *reinterpret_cast<const int4*>(&srcv[e0]);
      int4 d4 = *reinterpret_cast<const int4*>(&dstv[e0]);
      int4 t4 = *reinterpret_cast<const int4*>(&etype[e0]);
      float4 a4v = *reinterpret_cast<const float4*>(&eattr[e0]);
      int p0 = atomicAdd(&cursor3[t4.x * n + d4.x], 1);
      kattr[p0] = make_int2(s4.x, __float_as_int(a4v.x));
      int p1 = atomicAdd(&cursor3[t4.y * n + d4.y], 1);
      kattr[p1] = make_int2(s4.y, __float_as_int(a4v.y));
      int p2 = atomicAdd(&cursor3[t4.z * n + d4.z], 1);
      kattr[p2] = make_int2(s4.z, __float_as_int(a4v.z));
      int p3 = atomicAdd(&cursor3[t4.w * n + d4.w], 1);
      kattr[p3] = make_int2(s4.w, __float_as_int(a4v.w));
    } else {
      for (int t = 0; t < 4; ++t) {
        int e = e0 + t;
        if (e < E) {
          int p = atomicAdd(&cursor3[etype[e] * n + dstv[e]], 1);
          kattr[p] = make_int2(srcv[e], __float_as_int(eattr[e]));
        }
      }
    }
  }
}

// ---------------- aggregation over (r,dst) segments --------------------------
// One 16-lane group per segment (seg = r*N+dst); gathers 256B rows from the
// 12.8MB src-feature buffer (L2/L3-hot). Writes UNNORMALIZED hagg (bf16) +
// den partial; empty segments write zeros (required by the downstream GEMM).
__global__ __launch_bounds__(256) void agg_seg_kernel(
    const int* __restrict__ rowptr3, const int2* __restrict__ kattr,
    const float* __restrict__ sq, const float* __restrict__ sk,
    const __hip_bfloat16* __restrict__ feat, const float* __restrict__ cscal,
    __hip_bfloat16* __restrict__ hagg, float* __restrict__ den, int n, int m3) {
  const int wave = threadIdx.x >> 6, lane = threadIdx.x & 63;
  const int g = lane >> 4;     // segment slot within wave
  const int sub = lane & 15;   // 8-col chunk
  const int seg = blockIdx.x * 16 + wave * 4 + g;
  if (seg >= m3) return;
  const float c = cscal[0];
  const int r = (seg >= 2 * n) ? 2 : ((seg >= n) ? 1 : 0);
  const float* skr = sk + (size_t)r * n;

  const int start = rowptr3[seg];
  const int len = rowptr3[seg + 1] - start;
  const float sv = sq[seg];

  float acc[8];
#pragma unroll
  for (int t = 0; t < 8; ++t) acc[t] = 0.f;
  float dn = 0.f;

  for (int j0 = 0; j0 < len; j0 += 4) {
    int2 ka[4];
#pragma unroll
    for (int t = 0; t < 4; ++t) {
      int idx = j0 + t;
      ka[t] = kattr[start + (idx < len ? idx : 0)];
    }
    float w[4];
    bf16x8 f[4];
#pragma unroll
    for (int t = 0; t < 4; ++t) {
      int src = ka[t].x;
      float l = sv + skr[src] + c * __int_as_float(ka[t].y);
      l = l > 0.f ? l : 0.2f * l;
      w[t] = (j0 + t < len) ? __expf(l) : 0.f;
      f[t] = *reinterpret_cast<const bf16x8*>(feat + ((size_t)src << 7) + sub * 8);
    }
#pragma unroll
    for (int t = 0; t < 8; ++t)
      acc[t] += w[0] * (float)f[0][t] + w[1] * (float)f[1][t] +
                w[2] * (float)f[2][t] + w[3] * (float)f[3][t];
    dn += (w[0] + w[1]) + (w[2] + w[3]);
  }

  union { __hip_bfloat16 h[8]; int4 v; } pk;
#pragma unroll
  for (int t = 0; t < 8; ++t) pk.h[t] = __float2bfloat16(acc[t]);
  *reinterpret_cast<int4*>(hagg + ((size_t)seg << 7) + sub * 8) = pk.v;
  if (sub == 0) den[seg] = dn;
}

// ---------------- GEMM over hagg: out_m = (sum_r hagg[r,m] . W_r)/den + b ----
// 128 rows/block; acc accumulates across the 3 relations (A-frags re-loaded per
// relation from hagg, W_r staged in LDS as before). FINAL=0: relu -> bf16 hb +
// next layer's sq2/sk2 epilogue (h . W2q / W2k via wqk LDS). FINAL=1: f32 out.
template <int FINAL>
__global__ __launch_bounds__(256) void gemm_ho_kernel(
    const __hip_bfloat16* __restrict__ hagg, const float* __restrict__ den,
    const __hip_bfloat16* __restrict__ wt, const float* __restrict__ bias,
    const float* __restrict__ wqk2,  // [wq2 384][wk2 384], FINAL=0 only
    __hip_bfloat16* __restrict__ hb, float* __restrict__ sq2, float* __restrict__ sk2,
    float* __restrict__ outf, int n) {
  __shared__ __hip_bfloat16 wlds[16 * 128 * 8];  // 32 KB
  __shared__ float w2ls[768];
  const int base = blockIdx.x * 128;
  const int tid = threadIdx.x;
  const int wave = tid >> 6, lane = tid & 63;
  const int quad = lane >> 4, c16 = lane & 15;

  if (FINAL == 0) {
    for (int i = tid; i < 768; i += 256) w2ls[i] = wqk2[i];
  }

  bf16x8 zf;
#pragma unroll
  for (int j = 0; j < 8; ++j) zf[j] = (__bf16)0.0f;

  f32x4 acc[2][8];
#pragma unroll
  for (int h = 0; h < 2; ++h)
#pragma unroll
    for (int ot = 0; ot < 8; ++ot) acc[h][ot] = (f32x4){0.f, 0.f, 0.f, 0.f};

  for (int r = 0; r < 3; ++r) {
    if (r) __syncthreads();  // previous relation's LDS reads done
    {
      const int4* src = reinterpret_cast<const int4*>(wt + ((size_t)r << 14));
      int4* dst = reinterpret_cast<int4*>(wlds);
#pragma unroll
      for (int i = 0; i < 8; ++i) dst[tid + i * 256] = src[tid + i * 256];
    }
    // A-frags for this relation (global, independent of LDS)
    bf16x8 af[2][4];
#pragma unroll
    for (int h = 0; h < 2; ++h) {
      int m = base + wave * 32 + h * 16 + c16;
#pragma unroll
      for (int ks = 0; ks < 4; ++ks) {
        af[h][ks] = (m < n)
            ? *reinterpret_cast<const bf16x8*>(
                  hagg + (((size_t)r * n + m) << 7) + ks * 32 + quad * 8)
            : zf;
      }
    }
    __syncthreads();

#pragma unroll
    for (int ks = 0; ks < 4; ++ks) {
#pragma unroll
      for (int ot = 0; ot < 8; ++ot) {
        bf16x8 bfrag = *reinterpret_cast<const bf16x8*>(
            &wlds[(((ks * 4 + quad) * 128) + ot * 16 + c16) * 8]);
        acc[0][ot] = __builtin_amdgcn_mfma_f32_16x16x32_bf16(bfrag, af[0][ks], acc[0][ot], 0, 0, 0);
        acc[1][ot] = __builtin_amdgcn_mfma_f32_16x16x32_bf16(bfrag, af[1][ks], acc[1][ot], 0, 0, 0);
      }
    }
  }

#pragma unroll
  for (int h = 0; h < 2; ++h) {
    const int grow = base + wave * 32 + h * 16 + c16;
    const bool ok = grow < n;
    float dtot = ok ? (den[grow] + den[n + grow] + den[2 * n + grow]) : 1.f;
    float inv = 1.0f / (dtot + 1e-16f);
    if (FINAL == 0) {
      float s6[6];
#pragma unroll
      for (int j = 0; j < 6; ++j) s6[j] = 0.f;
#pragma unroll
      for (int ot = 0; ot < 8; ++ot) {
        const int col = ot * 16 + quad * 4;
        f32x4 bv = *reinterpret_cast<const f32x4*>(bias + col);
        f32x4 a = acc[h][ot];
        union { __hip_bfloat16 hh[4]; uint2 u; } pk;
#pragma unroll
        for (int j = 0; j < 4; ++j) {
          float v = fmaxf(a[j] * inv + bv[j], 0.f);
          pk.hh[j] = __float2bfloat16(v);
          s6[0] += v * w2ls[col + j];
          s6[1] += v * w2ls[128 + col + j];
          s6[2] += v * w2ls[256 + col + j];
          s6[3] += v * w2ls[384 + col + j];
          s6[4] += v * w2ls[512 + col + j];
          s6[5] += v * w2ls[640 + col + j];
        }
        if (ok)
          *reinterpret_cast<uint2*>(hb + ((size_t)grow << 7) + col) = pk.u;
      }
#pragma unroll
      for (int j = 0; j < 6; ++j) {
        s6[j] += __shfl_xor(s6[j], 16, 64);
        s6[j] += __shfl_xor(s6[j], 32, 64);
      }
      if (quad == 0 && ok) {
        sq2[grow] = s6[0]; sq2[n + grow] = s6[1]; sq2[2 * n + grow] = s6[2];
        sk2[grow] = s6[3]; sk2[n + grow] = s6[4]; sk2[2 * n + grow] = s6[5];
      }
    } else {
      if (ok) {
#pragma unroll
        for (int ot = 0; ot < 8; ++ot) {
          const int col = ot * 16 + quad * 4;
          f32x4 bv = *reinterpret_cast<const f32x4*>(bias + col);
          f32x4 a = acc[h][ot];
          f32x4 o;
#pragma unroll
          for (int j = 0; j < 4; ++j) o[j] = a[j] * inv + bv[j];
          *reinterpret_cast<f32x4*>(outf + (size_t)grow * CDIM + col) = o;
        }
      }
    }
  }
}

// ---------------- launcher ----------------

extern "C" void kernel_launch(void* const* d_in, const int* in_sizes, int n_in,
                              void* d_out, int out_size, void* d_ws, size_t ws_size,
                              hipStream_t stream) {
  const float* x     = (const float*)d_in[0];
  const int*   eidx  = (const int*)d_in[1];
  const int*   etype = (const int*)d_in[2];
  const float* eattr = (const float*)d_in[3];
  const float* w1  = (const float*)d_in[4];
  const float* q1  = (const float*)d_in[5];
  const float* k1  = (const float*)d_in[6];
  const float* le1 = (const float*)d_in[7];
  const float* e1  = (const float*)d_in[8];
  const float* b1  = (const float*)d_in[9];
  const float* w2  = (const float*)d_in[10];
  const float* q2  = (const float*)d_in[11];
  const float* k2  = (const float*)d_in[12];
  const float* le2 = (const float*)d_in[13];
  const float* e2  = (const float*)d_in[14];
  const float* b2  = (const float*)d_in[15];

  const int N = in_sizes[0] / CDIM;           // 50000
  const int E = in_sizes[2];                  // 500000
  const int R = in_sizes[4] / (CDIM * CDIM);  // 3
  const int M3 = R * N;                       // 150000 segments
  const int* srcv = eidx;
  const int* dstv = eidx + E;

  char* p = (char*)d_ws;
  auto alloc = [&](size_t bytes) -> void* {
    void* q = (void*)p;
    p += (bytes + 255) & ~(size_t)255;
    return q;
  };
  float* sq1      = (float*)alloc((size_t)M3 * 4);
  float* sk1      = (float*)alloc((size_t)M3 * 4);
  float* sq2      = (float*)alloc((size_t)M3 * 4);
  float* sk2      = (float*)alloc((size_t)M3 * 4);
  int*   deg3     = (int*)alloc((size_t)M3 * 4);
  int*   rowptr3  = (int*)alloc((size_t)(M3 + 1) * 4);
  int*   cursor3  = (int*)alloc((size_t)M3 * 4);
  int*   partials = (int*)alloc(4096);
  int2*  kattr    = (int2*)alloc((size_t)E * 8);
  __hip_bfloat16* wt = (__hip_bfloat16*)alloc((size_t)2 * R * CDIM * CDIM * 2);
  float* cscal    = (float*)alloc(256);
  float* wqk      = (float*)alloc(1536 * 4);
  __hip_bfloat16* xb    = (__hip_bfloat16*)alloc((size_t)N * CDIM * 2);
  __hip_bfloat16* hb    = (__hip_bfloat16*)alloc((size_t)N * CDIM * 2);
  __hip_bfloat16* hagg1 = (__hip_bfloat16*)alloc((size_t)M3 * CDIM * 2);
  __hip_bfloat16* hagg2 = (__hip_bfloat16*)alloc((size_t)M3 * CDIM * 2);
  float* den1     = (float*)alloc((size_t)M3 * 4);
  float* den2     = (float*)alloc((size_t)M3 * 4);

  size_t needed = (size_t)(p - (char*)d_ws);
  if (needed > ws_size) {
    sentinel_kernel<<<1, 64, 0, stream>>>((float*)d_out);
    return;
  }

  float* outp = (float*)d_out;

  const int eg4 = (E + 1023) / 1024;            // 489 (4 edges/thread)
  const int nb3 = (M3 + 4095) / 4096;           // 37 (<=64 for scan3 prefix)
  const int NX = (N + 127) / 128;               // 391
  const int NA = (M3 + 15) / 16;                // 9375 agg blocks
  const int perW = R * 2048;

  // 1) zero deg3
  hipMemsetAsync(deg3, 0, (size_t)M3 * 4, stream);

  // 2) prep (wt transpose + consts + wqk) + hist3
  prep_hist_kernel<<<49 + eg4, 256, 0, stream>>>(w1, w2, wt, q1, k1, q2, k2,
                                                 le1, e1, le2, e2, cscal, wqk,
                                                 dstv, etype, deg3, perW, N, E);

  // 3-4) CSR scans over 3N
  scan1_kernel<<<nb3, 256, 0, stream>>>(deg3, rowptr3, partials, M3);
  scan3_kernel<<<(M3 + 1 + 255) / 256, 256, 0, stream>>>(rowptr3, cursor3,
                                                         partials, nb3, M3, E);

  // 5) sq1/sk1 + xb cast (blocks [0,NX)) + scatter (blocks [NX,NX+eg4))
  sqskxb_scatter_kernel<<<NX + eg4, 256, 0, stream>>>(x, wqk, xb, sq1, sk1,
                                                      srcv, dstv, etype, eattr,
                                                      cursor3, kattr, NX, N, E);

  // 6) aggregate layer 1 (gather xb) -> hagg1, den1
  agg_seg_kernel<<<NA, 256, 0, stream>>>(rowptr3, kattr, sq1, sk1, xb,
                                         cscal + 0, hagg1, den1, N, M3);

  // 7) h = relu((sum_r hagg1_r . W1_r)/den + b1) -> hb bf16 + sq2/sk2
  gemm_ho_kernel<0><<<NX, 256, 0, stream>>>(hagg1, den1, wt, b1, wqk + 768,
                                            hb, sq2, sk2, nullptr, N);

  // 8) aggregate layer 2 (gather hb) -> hagg2, den2
  agg_seg_kernel<<<NA, 256, 0, stream>>>(rowptr3, kattr, sq2, sk2, hb,
                                         cscal + 1, hagg2, den2, N, M3);

  // 9) out = (sum_r hagg2_r . W2_r)/den + b2 -> f32
  gemm_ho_kernel<1><<<NX, 256, 0, stream>>>(hagg2, den2,
                                            wt + (size_t)R * CDIM * CDIM, b2,
                                            nullptr, nullptr, nullptr, nullptr,
                                            outp, N);
}

// Round 14
// 240.259 us; speedup vs baseline: 1.1778x; 1.1778x over previous
//
#include <hip/hip_runtime.h>
#include <hip/hip_bf16.h>
#include <math.h>

typedef __bf16 bf16x8 __attribute__((ext_vector_type(8)));
typedef float f32x4 __attribute__((ext_vector_type(4)));

#define CDIM 128

__global__ void sentinel_kernel(float* outf) {
  if (threadIdx.x == 0) outf[0] = 12345.0f;  // ws_size too small signature
}

// ---------------- prep + hist fused (deg pre-zeroed by hipMemsetAsync) -------
// blocks [0,48): wt[v][r][kb][o][j] = w_v[r][kb*8+j][o]
// block 48: c = le.e consts
// blocks [49,...): hist atomics, 4 edges/thread
__global__ __launch_bounds__(256) void prep_hist_kernel(
    const float* __restrict__ w1, const float* __restrict__ w2,
    __hip_bfloat16* __restrict__ wt,
    const float* __restrict__ le1, const float* __restrict__ e1,
    const float* __restrict__ le2, const float* __restrict__ e2,
    float* __restrict__ outc, const int* __restrict__ dstv,
    int* __restrict__ deg, int perW, int E) {
  const int b = blockIdx.x;
  const int tid = threadIdx.x;
  if (b < 48) {
    int t = b * 256 + tid;
    if (t >= perW * 2) return;
    const float* w = (t < perW) ? w1 : w2;
    int tt = (t < perW) ? t : t - perW;
    int r = tt >> 11;
    int rem = tt & 2047;
    int kb = rem >> 7;
    int o = rem & 127;
    const float* wr = w + ((size_t)r << 14);
    union { __hip_bfloat16 h[8]; int4 v; } u;
#pragma unroll
    for (int j = 0; j < 8; ++j)
      u.h[j] = __float2bfloat16(wr[(size_t)(kb * 8 + j) * CDIM + o]);
    *reinterpret_cast<int4*>(wt + (size_t)t * 8) = u.v;
  } else if (b == 48) {
    if (tid < 64) {
      float v1 = le1[tid] * e1[tid] + le1[tid + 64] * e1[tid + 64];
      float v2 = le2[tid] * e2[tid] + le2[tid + 64] * e2[tid + 64];
#pragma unroll
      for (int off = 32; off > 0; off >>= 1) {
        v1 += __shfl_xor(v1, off, 64);
        v2 += __shfl_xor(v2, off, 64);
      }
      if (tid == 0) { outc[0] = v1; outc[1] = v2; }
    }
  } else {
    int e0 = (b - 49) * 1024 + tid * 4;
    if (e0 + 3 < E) {
      int4 d4 = *reinterpret_cast<const int4*>(&dstv[e0]);
      atomicAdd(&deg[d4.x], 1);
      atomicAdd(&deg[d4.y], 1);
      atomicAdd(&deg[d4.z], 1);
      atomicAdd(&deg[d4.w], 1);
    } else {
      for (int t = 0; t < 4; ++t) {
        int e = e0 + t;
        if (e < E) atomicAdd(&deg[dstv[e]], 1);
      }
    }
  }
}

// ---------------- CSR scans ----------------

__global__ __launch_bounds__(256) void scan1_kernel(const int* __restrict__ deg,
                                                    int* __restrict__ rowptr,
                                                    int* __restrict__ partials, int n) {
  __shared__ int sh[256];
  int t = threadIdx.x;
  int base = blockIdx.x * 1024;
  int idx = base + t * 4;
  int v[4]; int s = 0;
#pragma unroll
  for (int j = 0; j < 4; ++j) { v[j] = (idx + j < n) ? deg[idx + j] : 0; s += v[j]; }
  sh[t] = s;
  __syncthreads();
  for (int off = 1; off < 256; off <<= 1) {
    int x = (t >= off) ? sh[t - off] : 0;
    __syncthreads();
    sh[t] += x;
    __syncthreads();
  }
  int excl = sh[t] - s;
  if (t == 255) partials[blockIdx.x] = sh[255];
  int run = excl;
#pragma unroll
  for (int j = 0; j < 4; ++j) {
    if (idx + j < n) rowptr[idx + j] = run;
    run += v[j];
  }
}

// scan3 with inline prefix of partials (nb <= 64)
__global__ __launch_bounds__(256) void scan3_kernel(int* __restrict__ rowptr,
                                                    int* __restrict__ cursor,
                                                    const int* __restrict__ partials,
                                                    int nb, int n, int E) {
  __shared__ int spfx[64];
  int t = threadIdx.x;
  if (t < 64) {
    int pv = (t < nb) ? partials[t] : 0;
    int v = pv;
#pragma unroll
    for (int off = 1; off < 64; off <<= 1) {
      int u = __shfl_up(v, off, 64);
      if (t >= off) v += u;
    }
    spfx[t] = v - pv;  // exclusive prefix
  }
  __syncthreads();
  int i = blockIdx.x * 256 + t;
  if (i < n) {
    int v = rowptr[i] + spfx[i >> 10];
    rowptr[i] = v;
    cursor[i] = v;
  } else if (i == n) {
    rowptr[n] = E;
  }
}

// ---------------- GEMM body: 128 rows/block, 3-relation loop -----------------
// x rows read ONCE into registers; weight tile re-staged per relation
// (wt is 96KB, L2-resident). BF16IN: layer-2 input is bf16 (no cvt).
// MFMA operands SWAPPED: acc = mfma(b, a) -> transposed C layout:
//   acc[h][ot][reg] = xw[m = base+wave*32+h*16+c16][o = ot*16+quad*4+reg]
template <int BF16IN>
__device__ __forceinline__ void gemm_body128(
    int tileb, const float* __restrict__ xf, const __hip_bfloat16* __restrict__ xb,
    const __hip_bfloat16* __restrict__ wt,
    const float* __restrict__ qv, const float* __restrict__ kv,
    __hip_bfloat16* __restrict__ xwout, float* __restrict__ sq,
    float* __restrict__ sk, int n, __hip_bfloat16* wlds, float* qls, float* kls) {
  const int base = tileb * 128;
  const int tid = threadIdx.x;
  const int wave = tid >> 6, lane = tid & 63;
  const int quad = lane >> 4, c16 = lane & 15;

  if (tid < 128) qls[tid] = qv[tid];
  else kls[tid - 128] = kv[tid - 128];

  bf16x8 zf;
#pragma unroll
  for (int j = 0; j < 8; ++j) zf[j] = (__bf16)0.0f;

  bf16x8 af[2][4];
#pragma unroll
  for (int h = 0; h < 2; ++h) {
    int m = base + wave * 32 + h * 16 + c16;
#pragma unroll
    for (int ks = 0; ks < 4; ++ks) {
      if (m < n) {
        if (BF16IN) {
          af[h][ks] = *reinterpret_cast<const bf16x8*>(
              xb + (size_t)m * CDIM + ks * 32 + quad * 8);
        } else {
          const float* xp = xf + (size_t)m * CDIM + ks * 32 + quad * 8;
          f32x4 x0 = *reinterpret_cast<const f32x4*>(xp);
          f32x4 x1 = *reinterpret_cast<const f32x4*>(xp + 4);
          bf16x8 a;
#pragma unroll
          for (int j = 0; j < 4; ++j) { a[j] = (__bf16)x0[j]; a[4 + j] = (__bf16)x1[j]; }
          af[h][ks] = a;
        }
      } else {
        af[h][ks] = zf;
      }
    }
  }

  for (int r = 0; r < 3; ++r) {
    if (r) __syncthreads();  // previous relation's LDS reads done
    {
      const int4* src = reinterpret_cast<const int4*>(wt + ((size_t)r << 14));
      int4* dst = reinterpret_cast<int4*>(wlds);
#pragma unroll
      for (int i = 0; i < 8; ++i) dst[tid + i * 256] = src[tid + i * 256];
    }
    __syncthreads();

    f32x4 acc[2][8];
#pragma unroll
    for (int h = 0; h < 2; ++h)
#pragma unroll
      for (int ot = 0; ot < 8; ++ot) acc[h][ot] = (f32x4){0.f, 0.f, 0.f, 0.f};

#pragma unroll
    for (int ks = 0; ks < 4; ++ks) {
#pragma unroll
      for (int ot = 0; ot < 8; ++ot) {
        bf16x8 b = *reinterpret_cast<const bf16x8*>(
            &wlds[(((ks * 4 + quad) * 128) + ot * 16 + c16) * 8]);
        acc[0][ot] = __builtin_amdgcn_mfma_f32_16x16x32_bf16(b, af[0][ks], acc[0][ot], 0, 0, 0);
        acc[1][ot] = __builtin_amdgcn_mfma_f32_16x16x32_bf16(b, af[1][ks], acc[1][ot], 0, 0, 0);
      }
    }

#pragma unroll
    for (int h = 0; h < 2; ++h) {
      const int grow = base + wave * 32 + h * 16 + c16;
      const bool ok = grow < n;
      __hip_bfloat16* rp = xwout + (((size_t)r * n + grow) << 7) + quad * 4;
      float s_q = 0.f, s_k = 0.f;
#pragma unroll
      for (int ot = 0; ot < 8; ++ot) {
        f32x4 a = acc[h][ot];
        f32x4 q4 = *reinterpret_cast<const f32x4*>(&qls[ot * 16 + quad * 4]);
        f32x4 k4 = *reinterpret_cast<const f32x4*>(&kls[ot * 16 + quad * 4]);
        s_q += a[0] * q4[0] + a[1] * q4[1] + a[2] * q4[2] + a[3] * q4[3];
        s_k += a[0] * k4[0] + a[1] * k4[1] + a[2] * k4[2] + a[3] * k4[3];
        if (ok) {
          union { __hip_bfloat16 b4[4]; uint2 u; } pk;
#pragma unroll
          for (int t = 0; t < 4; ++t) pk.b4[t] = __float2bfloat16(a[t]);
          *reinterpret_cast<uint2*>(rp + ot * 16) = pk.u;
        }
      }
      s_q += __shfl_xor(s_q, 16, 64);
      s_q += __shfl_xor(s_q, 32, 64);
      s_k += __shfl_xor(s_k, 16, 64);
      s_k += __shfl_xor(s_k, 32, 64);
      if (quad == 0 && ok) {
        sq[(size_t)r * n + grow] = s_q;
        sk[(size_t)r * n + grow] = s_k;
      }
    }
  }
}

// ---------------- gemm1 + scatter fused (independent work, block-split) ------
__global__ __launch_bounds__(256) void gemm_scatter_kernel(
    const float* __restrict__ xin, const __hip_bfloat16* __restrict__ wt,
    const float* __restrict__ qv, const float* __restrict__ kv,
    __hip_bfloat16* __restrict__ xwout, float* __restrict__ sq, float* __restrict__ sk,
    const int* __restrict__ srcv, const int* __restrict__ dstv,
    const int* __restrict__ etype, const float* __restrict__ eattr,
    int* __restrict__ cursor, int2* __restrict__ kattr,
    int NT, int n, int E) {
  __shared__ __hip_bfloat16 wlds[16 * 128 * 8];  // 32 KB
  __shared__ float qls[128], kls[128];
  const int b = blockIdx.x;
  if (b < NT) {
    gemm_body128<0>(b, xin, nullptr, wt, qv, kv, xwout, sq, sk, n, wlds, qls, kls);
  } else {
    int e0 = (b - NT) * 1024 + threadIdx.x * 4;
    if (e0 + 3 < E) {
      int4 s4 = *reinterpret_cast<const int4*>(&srcv[e0]);
      int4 d4 = *reinterpret_cast<const int4*>(&dstv[e0]);
      int4 t4 = *reinterpret_cast<const int4*>(&etype[e0]);
      float4 a4 = *reinterpret_cast<const float4*>(&eattr[e0]);
      int p0 = atomicAdd(&cursor[d4.x], 1);
      kattr[p0] = make_int2(t4.x * n + s4.x, __float_as_int(a4.x));
      int p1 = atomicAdd(&cursor[d4.y], 1);
      kattr[p1] = make_int2(t4.y * n + s4.y, __float_as_int(a4.y));
      int p2 = atomicAdd(&cursor[d4.z], 1);
      kattr[p2] = make_int2(t4.z * n + s4.z, __float_as_int(a4.z));
      int p3 = atomicAdd(&cursor[d4.w], 1);
      kattr[p3] = make_int2(t4.w * n + s4.w, __float_as_int(a4.w));
    } else {
      for (int t = 0; t < 4; ++t) {
        int e = e0 + t;
        if (e < E) {
          int p = atomicAdd(&cursor[dstv[e]], 1);
          kattr[p] = make_int2(etype[e] * n + srcv[e], __float_as_int(eattr[e]));
        }
      }
    }
  }
}

// layer 2: bf16 input (hb)
__global__ __launch_bounds__(256) void gemm_xw_bf16_kernel(
    const __hip_bfloat16* __restrict__ xin, const __hip_bfloat16* __restrict__ wt,
    const float* __restrict__ qv, const float* __restrict__ kv,
    __hip_bfloat16* __restrict__ xwout, float* __restrict__ sq, float* __restrict__ sk,
    int n) {
  __shared__ __hip_bfloat16 wlds[16 * 128 * 8];
  __shared__ float qls[128], kls[128];
  gemm_body128<1>(blockIdx.x, nullptr, xin, wt, qv, kv, xwout, sq, sk, n,
                  wlds, qls, kls);
}

// ---------------- aggregation: one 16-lane group per node --------------------
// 4 nodes/wave, 16 nodes/block. den and acc lane-local (no reductions); all 16
// lanes write the output row. Edge loop: 8 INDEPENDENT gather chains per
// iteration (was 4) -> deg<=8 nodes finish in one latency round-trip; no
// redundant loads. OUTBF16: layer-1 writes bf16+relu; layer-2 f32.
template <int OUTBF16>
__global__ __launch_bounds__(256) void aggregate_kernel(
    const int* __restrict__ rowptr, const int2* __restrict__ kattr,
    const float* __restrict__ sq, const float* __restrict__ sk,
    const __hip_bfloat16* __restrict__ xw, const float* __restrict__ bias,
    const float* __restrict__ cscal, float* __restrict__ outf,
    __hip_bfloat16* __restrict__ outb, int n) {
  const int wave = threadIdx.x >> 6, lane = threadIdx.x & 63;
  const int g = lane >> 4;     // node slot within wave
  const int sub = lane & 15;   // 8-col chunk within node row
  const int node = blockIdx.x * 16 + wave * 4 + g;
  if (node >= n) return;       // per-group predication; no barriers below
  const float c = cscal[0];
  const int n2 = n * 2;

  const int start = rowptr[node];
  const int deg = rowptr[node + 1] - start;
  const float s0 = sq[node], s1 = sq[n + node], s2 = sq[n2 + node];

  float acc[8];
#pragma unroll
  for (int t = 0; t < 8; ++t) acc[t] = 0.f;
  float den = 0.f;

  for (int j0 = 0; j0 < deg; j0 += 8) {
    // 8 independent gather chains (this group's node)
    int2 ka[8];
#pragma unroll
    for (int t = 0; t < 8; ++t) {
      int idx = j0 + t;
      ka[t] = kattr[start + (idx < deg ? idx : 0)];
    }
    float w[8];
    bf16x8 f[8];
#pragma unroll
    for (int t = 0; t < 8; ++t) {
      int kk = ka[t].x;
      float sv = (kk >= n2) ? s2 : ((kk >= n) ? s1 : s0);
      float l = sv + sk[kk] + c * __int_as_float(ka[t].y);
      l = l > 0.f ? l : 0.2f * l;
      w[t] = (j0 + t < deg) ? __expf(l) : 0.f;
      f[t] = *reinterpret_cast<const bf16x8*>(xw + ((size_t)kk << 7) + sub * 8);
    }
#pragma unroll
    for (int t = 0; t < 8; ++t)
      acc[t] += (w[0] * (float)f[0][t] + w[1] * (float)f[1][t] +
                 w[2] * (float)f[2][t] + w[3] * (float)f[3][t]) +
                (w[4] * (float)f[4][t] + w[5] * (float)f[5][t] +
                 w[6] * (float)f[6][t] + w[7] * (float)f[7][t]);
    den += ((w[0] + w[1]) + (w[2] + w[3])) + ((w[4] + w[5]) + (w[6] + w[7]));
  }

  float inv = 1.0f / (den + 1e-16f);
  f32x4 b0 = *reinterpret_cast<const f32x4*>(bias + sub * 8);
  f32x4 b1 = *reinterpret_cast<const f32x4*>(bias + sub * 8 + 4);
  f32x4 o0, o1;
#pragma unroll
  for (int t = 0; t < 4; ++t) {
    o0[t] = acc[t] * inv + b0[t];
    o1[t] = acc[4 + t] * inv + b1[t];
  }
  if (OUTBF16) {
    // relu + bf16 store (same rounding point as f32-store + later cvt)
    union { __hip_bfloat16 h[8]; int4 v; } pk;
#pragma unroll
    for (int t = 0; t < 4; ++t) {
      pk.h[t] = __float2bfloat16(fmaxf(o0[t], 0.f));
      pk.h[4 + t] = __float2bfloat16(fmaxf(o1[t], 0.f));
    }
    *reinterpret_cast<int4*>(outb + (size_t)node * CDIM + sub * 8) = pk.v;
  } else {
    float* op = outf + (size_t)node * CDIM + sub * 8;
    *reinterpret_cast<f32x4*>(op) = o0;
    *reinterpret_cast<f32x4*>(op + 4) = o1;
  }
}

// ---------------- launcher ----------------

extern "C" void kernel_launch(void* const* d_in, const int* in_sizes, int n_in,
                              void* d_out, int out_size, void* d_ws, size_t ws_size,
                              hipStream_t stream) {
  const float* x     = (const float*)d_in[0];
  const int*   eidx  = (const int*)d_in[1];
  const int*   etype = (const int*)d_in[2];
  const float* eattr = (const float*)d_in[3];
  const float* w1  = (const float*)d_in[4];
  const float* q1  = (const float*)d_in[5];
  const float* k1  = (const float*)d_in[6];
  const float* le1 = (const float*)d_in[7];
  const float* e1  = (const float*)d_in[8];
  const float* b1  = (const float*)d_in[9];
  const float* w2  = (const float*)d_in[10];
  const float* q2  = (const float*)d_in[11];
  const float* k2  = (const float*)d_in[12];
  const float* le2 = (const float*)d_in[13];
  const float* e2  = (const float*)d_in[14];
  const float* b2  = (const float*)d_in[15];

  const int N = in_sizes[0] / CDIM;           // 50000
  const int E = in_sizes[2];                  // 500000
  const int R = in_sizes[4] / (CDIM * CDIM);  // 3
  const int* srcv = eidx;
  const int* dstv = eidx + E;

  char* p = (char*)d_ws;
  auto alloc = [&](size_t bytes) -> void* {
    void* q = (void*)p;
    p += (bytes + 255) & ~(size_t)255;
    return q;
  };
  float* sq       = (float*)alloc((size_t)R * N * 4);
  float* sk       = (float*)alloc((size_t)R * N * 4);
  int*   deg      = (int*)alloc((size_t)N * 4);
  int*   rowptr   = (int*)alloc((size_t)(N + 1) * 4);
  int*   cursor   = (int*)alloc((size_t)N * 4);
  int*   partials = (int*)alloc(4096);
  int2*  kattr    = (int2*)alloc((size_t)E * 8);
  __hip_bfloat16* wt = (__hip_bfloat16*)alloc((size_t)2 * R * CDIM * CDIM * 2);
  float* cscal    = (float*)alloc(256);
  __hip_bfloat16* xw = (__hip_bfloat16*)alloc((size_t)R * N * CDIM * 2);
  __hip_bfloat16* hb = (__hip_bfloat16*)alloc((size_t)N * CDIM * 2);

  size_t needed = (size_t)(p - (char*)d_ws);
  if (needed > ws_size) {
    sentinel_kernel<<<1, 64, 0, stream>>>((float*)d_out);
    return;
  }

  float* outp = (float*)d_out;

  const int eg4 = (E + 1023) / 1024;          // 489 (4 edges/thread)
  const int nb = (N + 1023) / 1024;           // 49 (<=64 required by scan3 prefix)
  const int NT = (N + 127) / 128;             // 391 gemm tiles
  const int nodes16 = (N + 15) / 16;          // 3125 agg blocks
  const int perW = R * 2048;

  // 1) zero deg (stream-ordered, graph-capturable)
  hipMemsetAsync(deg, 0, (size_t)N * 4, stream);

  // 2) prep (wt transpose + consts) + hist, fused
  prep_hist_kernel<<<49 + eg4, 256, 0, stream>>>(w1, w2, wt, le1, e1, le2, e2,
                                                 cscal, dstv, deg, perW, E);

  // 3-4) CSR scans
  scan1_kernel<<<nb, 256, 0, stream>>>(deg, rowptr, partials, N);
  scan3_kernel<<<(N + 1 + 255) / 256, 256, 0, stream>>>(rowptr, cursor, partials, nb, N, E);

  // 5) gemm1 (blocks [0,NT)) + scatter (blocks [NT,NT+eg4)), fused
  gemm_scatter_kernel<<<NT + eg4, 256, 0, stream>>>(x, wt, q1, k1, xw, sq, sk,
                                                    srcv, dstv, etype, eattr,
                                                    cursor, kattr, NT, N, E);

  // 6) aggregate layer 1 -> bf16 hidden (relu)
  aggregate_kernel<1><<<nodes16, 256, 0, stream>>>(rowptr, kattr, sq, sk, xw, b1,
                                                   cscal + 0, nullptr, hb, N);

  // 7) gemm layer 2 (bf16 input)
  gemm_xw_bf16_kernel<<<NT, 256, 0, stream>>>(hb, wt + (size_t)R * CDIM * CDIM,
                                              q2, k2, xw, sq, sk, N);

  // 8) aggregate layer 2 -> f32 output
  aggregate_kernel<0><<<nodes16, 256, 0, stream>>>(rowptr, kattr, sq, sk, xw, b2,
                                                   cscal + 1, outp, nullptr, N);
}